// Round 4
// baseline (57503.864 us; speedup 1.0000x reference)
//
#include <hip/hip_runtime.h>

#define TT 512
#define BSZ 64
#define DD 512
#define HH 512
#define NGROUP 4
#define GBLK 64        // blocks per group
#define GBATCH 16      // batches per group

struct Params {
    const float* X;
    const float* Wx[4];   // W_xi, W_xf, W_xo, W_xc   [D][H] row-major
    const float* Wh[4];   // W_hi, W_hf, W_ho, W_hc   [H][H] row-major
    const float* bias[4]; // b_i, b_f, b_o, b_c       [H]
    float* Y;             // [B][T][H]
    float* hbuf;          // ws: 2 * B * H floats (double buffer)
    unsigned int* ctr;    // ws: NGROUP counters, 64-uint padded
};

__device__ __forceinline__ float fast_sigmoid(float x) {
    return 1.0f / (1.0f + __expf(-x));
}

__device__ __forceinline__ float fast_tanh(float x) {
    float ax = fabsf(x);
    float e  = __expf(-2.0f * ax);
    float r  = (1.0f - e) / (1.0f + e);
    return copysignf(r, x);
}

__global__ void init_ws(float* hbuf, unsigned int* ctr) {
    int i = blockIdx.x * blockDim.x + threadIdx.x;
    int stride = gridDim.x * blockDim.x;
    for (int k = i; k < 2 * BSZ * HH; k += stride) hbuf[k] = 0.0f;
    if (i < 8 * 64) ctr[i] = 0u;
}

// Persistent LSTM. 256 blocks x 256 threads, plain launch. LDS 146.5 KB ->
// 1 block/CU, all 256 co-resident (pattern proven in R2/R3).
// 4 groups x 64 blocks; group g owns batches [16g, 16g+16).
// Block k in group owns hidden units [8k, 8k+8) -> 32 gate columns.
// Thread (c = tid&31, s = tid>>5): col c (gate=c>>3, unit=c&7), K-slice
// [64s, 64s+64).
//
// REGISTER BUDGET (R2: 256 w-floats spilled, 22.7ms; R3: 128 w-floats +
// acc[16] + unroll temps ALSO spilled -> 118 GB scratch traffic, 54ms):
// this version keeps ONLY wh (64 floats = 16 float4) persistent; W_x lives
// in LDS with a [k][c] stride-33 layout (banks=(k+c)%32: conflict-free,
// 2-way s-alias = free). Live set ~130 VGPRs -> no spill.
__global__ __launch_bounds__(256, 1) void lstm_persist(Params p) {
    __shared__ float wx_lds[DD * 33];        // 66 KB: W_x slice, [k][c] pad-33
    __shared__ float hs[GBATCH * HH];        // 32 KB: h_{t-1}, 16 batches
    __shared__ float xs[GBATCH * DD];        // 32 KB: x_t, 16 batches
    __shared__ float part[GBATCH * 8 * 33];  // 16.9 KB: partials [bb][s][33(c)]

    const int bid  = blockIdx.x;
    const int g    = bid >> 6;             // group 0..3
    const int k    = bid & 63;             // block in group
    const int tid  = threadIdx.x;
    const int c    = tid & 31;             // col 0..31
    const int s    = tid >> 5;             // K-slice 0..7
    const int gate = c >> 3;
    const int jcol = k * 8 + (c & 7);      // weight-matrix column
    const int b0   = g * GBATCH;
    const int kb   = s * 64;               // K-slice start

    // ---- one-time: W_x slice (32 cols x 512 rows) into LDS, [k][c] ----
    for (int idx = tid; idx < 32 * DD; idx += 256) {
        int cc = idx & 31;
        int kk = idx >> 5;
        int gg = cc >> 3;
        int jc = k * 8 + (cc & 7);
        wx_lds[kk * 33 + cc] = p.Wx[gg][kk * HH + jc];
    }

    // ---- one-time: W_h slice into registers (64 floats ONLY) ----
    const float* WhG = p.Wh[gate];
    float4 wh4[16];
#pragma unroll
    for (int i = 0; i < 16; ++i) {
        int kk = kb + i * 4;
        wh4[i] = make_float4(WhG[(kk + 0) * HH + jcol], WhG[(kk + 1) * HH + jcol],
                             WhG[(kk + 2) * HH + jcol], WhG[(kk + 3) * HH + jcol]);
    }

    // Cell-update thread state (threads 0..127): (batch bbu, unit jju)
    const int bbu = tid >> 3;              // 0..15
    const int jju = tid & 7;
    const int ju  = k * 8 + jju;
    float cst = 0.0f;
    float bI = 0.f, bF = 0.f, bO = 0.f, bC = 0.f;
    if (tid < 128) {
        bI = p.bias[0][ju];
        bF = p.bias[1][ju];
        bO = p.bias[2][ju];
        bC = p.bias[3][ju];
    }

    unsigned int* ctrp = p.ctr + g * 64;
    const float4* xsrc = (const float4*)p.X;
    float4* hs4 = (float4*)hs;
    float4* xs4 = (float4*)xs;

    __syncthreads();   // wx_lds ready

    for (int t = 0; t < TT; ++t) {
        // ---- 1. stage x_t (no cross-block dependency) ----
#pragma unroll
        for (int u = 0; u < 8; ++u) {
            int idx = tid + u * 256;           // 0..2047
            int b   = idx >> 7;                // 0..15
            int dd  = idx & 127;               // float4 within row
            xs4[b * 128 + dd] = xsrc[((size_t)(b0 + b) * TT + t) * 128 + dd];
        }
        __syncthreads();

        // ---- 2. x-projection FMAs: weights streamed from LDS ----
        float acc[16];
#pragma unroll
        for (int bb = 0; bb < 16; ++bb) acc[bb] = 0.0f;
#pragma unroll
        for (int i4 = 0; i4 < 16; ++i4) {
            const int kk = kb + i4 * 4;
            const float w0 = wx_lds[(kk + 0) * 33 + c];
            const float w1 = wx_lds[(kk + 1) * 33 + c];
            const float w2 = wx_lds[(kk + 2) * 33 + c];
            const float w3 = wx_lds[(kk + 3) * 33 + c];
#pragma unroll
            for (int bb = 0; bb < 16; ++bb) {
                float4 xv = xs4[bb * 128 + (kk >> 2)];  // 32-lane broadcast
                float a = acc[bb];
                a = fmaf(xv.x, w0, a);
                a = fmaf(xv.y, w1, a);
                a = fmaf(xv.z, w2, a);
                a = fmaf(xv.w, w3, a);
                acc[bb] = a;
            }
        }

        // ---- 3. wait for h_{t-1} from all 64 group blocks (overlapped) ----
        const unsigned int need = (unsigned int)(GBLK * t);
        while (__hip_atomic_load(ctrp, __ATOMIC_ACQUIRE, __HIP_MEMORY_SCOPE_AGENT) < need) {
            __builtin_amdgcn_s_sleep(1);
        }

        // ---- 4. stage h_{t-1} ----
        const float4* hsrc = (const float4*)(p.hbuf + (size_t)(t & 1) * BSZ * HH);
#pragma unroll
        for (int u = 0; u < 8; ++u) {
            int idx = tid + u * 256;
            int b   = idx >> 7;
            int dd  = idx & 127;
            hs4[b * 128 + dd] = hsrc[(b0 + b) * 128 + dd];
        }
        __syncthreads();

        // ---- 5. recurrent FMAs: weights from registers ----
#pragma unroll
        for (int i4 = 0; i4 < 16; ++i4) {
            const float4 w = wh4[i4];
#pragma unroll
            for (int bb = 0; bb < 16; ++bb) {
                float4 hv = hs4[bb * 128 + s * 16 + i4];
                float a = acc[bb];
                a = fmaf(hv.x, w.x, a);
                a = fmaf(hv.y, w.y, a);
                a = fmaf(hv.z, w.z, a);
                a = fmaf(hv.w, w.w, a);
                acc[bb] = a;
            }
        }

        // ---- 6. write partials (stride 33: 2-way max, measured 0 in R3) ----
#pragma unroll
        for (int bb = 0; bb < 16; ++bb)
            part[(bb * 8 + s) * 33 + c] = acc[bb];
        __syncthreads();

        // ---- 7. cell update ----
        if (tid < 128) {
            float v0 = bI, v1 = bF, v2 = bO, v3 = bC;
#pragma unroll
            for (int ss = 0; ss < 8; ++ss) {
                const float* pr = &part[(bbu * 8 + ss) * 33];
                v0 += pr[0 * 8 + jju];
                v1 += pr[1 * 8 + jju];
                v2 += pr[2 * 8 + jju];
                v3 += pr[3 * 8 + jju];
            }
            float I  = fast_sigmoid(v0);
            float F  = fast_sigmoid(v1);
            float O  = fast_sigmoid(v2);
            float Cd = fast_tanh(v3);
            cst = fmaf(F, cst, I * Cd);
            float h = O * fast_tanh(cst);
            p.hbuf[(size_t)((t + 1) & 1) * BSZ * HH + (b0 + bbu) * HH + ju] = h;
            p.Y[((size_t)(b0 + bbu) * TT + t) * HH + ju] = h;
        }
        __syncthreads();   // drains h stores (vmcnt) + part reads done

        // ---- 8. publish: agent-scope release (proven in R2/R3) ----
        if (tid == 0) {
            __hip_atomic_fetch_add(ctrp, 1u, __ATOMIC_RELEASE, __HIP_MEMORY_SCOPE_AGENT);
        }
    }
}

extern "C" void kernel_launch(void* const* d_in, const int* in_sizes, int n_in,
                              void* d_out, int out_size, void* d_ws, size_t ws_size,
                              hipStream_t stream) {
    Params p;
    p.X       = (const float*)d_in[0];
    p.Wx[0]   = (const float*)d_in[1];
    p.Wh[0]   = (const float*)d_in[2];
    p.bias[0] = (const float*)d_in[3];
    p.Wx[1]   = (const float*)d_in[4];
    p.Wh[1]   = (const float*)d_in[5];
    p.bias[1] = (const float*)d_in[6];
    p.Wx[2]   = (const float*)d_in[7];
    p.Wh[2]   = (const float*)d_in[8];
    p.bias[2] = (const float*)d_in[9];
    p.Wx[3]   = (const float*)d_in[10];
    p.Wh[3]   = (const float*)d_in[11];
    p.bias[3] = (const float*)d_in[12];
    p.Y       = (float*)d_out;
    p.hbuf    = (float*)d_ws;
    p.ctr     = (unsigned int*)((char*)d_ws + (size_t)2 * BSZ * HH * sizeof(float));

    // ws is poisoned 0xAA before every timed launch: zero h0 double-buffer + counters
    init_ws<<<64, 256, 0, stream>>>(p.hbuf, p.ctr);

    lstm_persist<<<dim3(256), dim3(256), 0, stream>>>(p);
}

// Round 5
// 8155.572 us; speedup vs baseline: 7.0509x; 7.0509x over previous
//
#include <hip/hip_runtime.h>

#define TT 512
#define BSZ 64
#define DD 512
#define HH 512
#define NGROUP 4
#define GBLK 64        // blocks per group
#define GBATCH 16      // batches per group

struct Params {
    const float* X;
    const float* Wx[4];   // W_xi, W_xf, W_xo, W_xc   [D][H] row-major
    const float* Wh[4];   // W_hi, W_hf, W_ho, W_hc   [H][H] row-major
    const float* bias[4]; // b_i, b_f, b_o, b_c       [H]
    float* Y;             // [B][T][H]
    float* hbuf;          // ws: 2 * B * H floats (double buffer)
    unsigned int* ctr;    // ws: NGROUP counters, 64-uint padded
};

__device__ __forceinline__ float fast_sigmoid(float x) {
    return 1.0f / (1.0f + __expf(-x));
}

__device__ __forceinline__ float fast_tanh(float x) {
    float ax = fabsf(x);
    float e  = __expf(-2.0f * ax);
    float r  = (1.0f - e) / (1.0f + e);
    return copysignf(r, x);
}

__global__ void init_ws(float* hbuf, unsigned int* ctr) {
    int i = blockIdx.x * blockDim.x + threadIdx.x;
    int stride = gridDim.x * blockDim.x;
    for (int k = i; k < 2 * BSZ * HH; k += stride) hbuf[k] = 0.0f;
    if (i < 8 * 64) ctr[i] = 0u;
}

// Persistent LSTM. 256 blocks x 256 threads. 146.5 KB LDS -> 1 block/CU.
// 4 groups x 64 blocks; group g owns batches [16g, 16g+16).
// Block k owns hidden units [8k, 8k+8) -> 32 gate columns.
// Thread (c = tid&31, s = tid>>5): col c (gate=c>>3), K-slice [64s, 64s+64).
//
// SPILL HISTORY: R2 (256 reg w-floats) spilled; R3 (128) spilled; R4 (64 regs
// + LDS wx but FULL 16x16 unroll of both FMA loops = 2x256 hoisted ds_read_b128
// live ranges) ALSO spilled -> 77 GB scratch writes. Root cause is
// scheduler-driven live-range blowup, so this version caps it:
//   - x-loop: #pragma unroll 1 (weights from LDS, no const-index need)
//   - h-loop: full unroll (wh4[] reg array NEEDS constant indices) but
//     sched_barrier(0) after each K-chunk -> <=16 b128 loads in flight.
// Barrier: tid0-only RELAXED spin (acquire-per-poll in R2-R4 invalidated
// L1/L2 every ~100ns from 64Ki threads), then one acquire fence + barrier.
__global__ __launch_bounds__(256, 1) void lstm_persist(Params p) {
    __shared__ float wx_lds[DD * 33];        // 66 KB: W_x slice, [k][c] pad-33
    __shared__ float hs[GBATCH * HH];        // 32 KB: h_{t-1}, 16 batches
    __shared__ float xs[GBATCH * DD];        // 32 KB: x_t, 16 batches
    __shared__ float part[GBATCH * 8 * 33];  // 16.9 KB: partials [bb][s][33(c)]

    const int bid  = blockIdx.x;
    const int g    = bid >> 6;             // group 0..3
    const int k    = bid & 63;             // block in group
    const int tid  = threadIdx.x;
    const int c    = tid & 31;             // col 0..31
    const int s    = tid >> 5;             // K-slice 0..7
    const int gate = c >> 3;
    const int jcol = k * 8 + (c & 7);      // weight-matrix column
    const int b0   = g * GBATCH;
    const int kb   = s * 64;               // K-slice start

    // ---- one-time: W_x slice (32 cols x 512 rows) into LDS, [k][c] ----
    for (int idx = tid; idx < 32 * DD; idx += 256) {
        int cc = idx & 31;
        int kk = idx >> 5;
        int gg = cc >> 3;
        int jc = k * 8 + (cc & 7);
        wx_lds[kk * 33 + cc] = p.Wx[gg][kk * HH + jc];
    }

    // ---- one-time: W_h slice into registers (64 floats) ----
    const float* WhG = p.Wh[gate];
    float4 wh4[16];
#pragma unroll
    for (int i = 0; i < 16; ++i) {
        int kk = kb + i * 4;
        wh4[i] = make_float4(WhG[(kk + 0) * HH + jcol], WhG[(kk + 1) * HH + jcol],
                             WhG[(kk + 2) * HH + jcol], WhG[(kk + 3) * HH + jcol]);
    }

    // Cell-update thread state (threads 0..127): (batch bbu, unit jju)
    const int bbu = tid >> 3;              // 0..15
    const int jju = tid & 7;
    const int ju  = k * 8 + jju;
    float cst = 0.0f;
    float bI = 0.f, bF = 0.f, bO = 0.f, bC = 0.f;
    if (tid < 128) {
        bI = p.bias[0][ju];
        bF = p.bias[1][ju];
        bO = p.bias[2][ju];
        bC = p.bias[3][ju];
    }

    unsigned int* ctrp = p.ctr + g * 64;
    const float4* xsrc = (const float4*)p.X;
    float4* hs4 = (float4*)hs;
    float4* xs4 = (float4*)xs;

    __syncthreads();   // wx_lds ready

    for (int t = 0; t < TT; ++t) {
        // ---- 1. stage x_t (no cross-block dependency) ----
#pragma unroll
        for (int u = 0; u < 8; ++u) {
            int idx = tid + u * 256;           // 0..2047
            int b   = idx >> 7;                // 0..15
            int dd  = idx & 127;               // float4 within row
            xs4[b * 128 + dd] = xsrc[((size_t)(b0 + b) * TT + t) * 128 + dd];
        }
        __syncthreads();

        // ---- 2. x-projection FMAs, weights streamed from LDS.
        //      unroll 1: body = 4 ds_read_b32 + 16 ds_read_b128 + 64 FMA ----
        float acc[16];
#pragma unroll
        for (int bb = 0; bb < 16; ++bb) acc[bb] = 0.0f;
#pragma unroll 1
        for (int i4 = 0; i4 < 16; ++i4) {
            const int kk = kb + i4 * 4;
            const float w0 = wx_lds[(kk + 0) * 33 + c];
            const float w1 = wx_lds[(kk + 1) * 33 + c];
            const float w2 = wx_lds[(kk + 2) * 33 + c];
            const float w3 = wx_lds[(kk + 3) * 33 + c];
            const float4* xp = &xs4[s * 16 + i4];
#pragma unroll
            for (int bb = 0; bb < 16; ++bb) {
                float4 xv = xp[bb * 128];      // 32-lane broadcast
                float a = acc[bb];
                a = fmaf(xv.x, w0, a);
                a = fmaf(xv.y, w1, a);
                a = fmaf(xv.z, w2, a);
                a = fmaf(xv.w, w3, a);
                acc[bb] = a;
            }
            __builtin_amdgcn_sched_barrier(0);
        }

        // ---- 3. wait for h_{t-1}: tid0-only relaxed spin, then acq fence ----
        if (tid == 0) {
            const unsigned int need = (unsigned int)(GBLK * t);
            while (__hip_atomic_load(ctrp, __ATOMIC_RELAXED, __HIP_MEMORY_SCOPE_AGENT) < need) {
                __builtin_amdgcn_s_sleep(2);
            }
            __builtin_amdgcn_fence(__ATOMIC_ACQUIRE, "agent");  // inv L1+L2 (this CU/XCD)
        }
        __syncthreads();

        // ---- 4. stage h_{t-1} ----
        const float4* hsrc = (const float4*)(p.hbuf + (size_t)(t & 1) * BSZ * HH);
#pragma unroll
        for (int u = 0; u < 8; ++u) {
            int idx = tid + u * 256;
            int b   = idx >> 7;
            int dd  = idx & 127;
            hs4[b * 128 + dd] = hsrc[(b0 + b) * 128 + dd];
        }
        __syncthreads();

        // ---- 5. recurrent FMAs, weights from registers. Full unroll is
        //      REQUIRED (wh4[] const indices); sched_barrier bounds the
        //      in-flight loads to one 16-b128 chunk ----
#pragma unroll
        for (int i4 = 0; i4 < 16; ++i4) {
            const float4 w = wh4[i4];
            const float4* hp = &hs4[s * 16 + i4];
#pragma unroll
            for (int bb = 0; bb < 16; ++bb) {
                float4 hv = hp[bb * 128];      // 32-lane broadcast
                float a = acc[bb];
                a = fmaf(hv.x, w.x, a);
                a = fmaf(hv.y, w.y, a);
                a = fmaf(hv.z, w.z, a);
                a = fmaf(hv.w, w.w, a);
                acc[bb] = a;
            }
            __builtin_amdgcn_sched_barrier(0);
        }

        // ---- 6. write partials (stride 33: conflict-free) ----
#pragma unroll
        for (int bb = 0; bb < 16; ++bb)
            part[(bb * 8 + s) * 33 + c] = acc[bb];
        __syncthreads();

        // ---- 7. cell update ----
        if (tid < 128) {
            float v0 = bI, v1 = bF, v2 = bO, v3 = bC;
#pragma unroll
            for (int ss = 0; ss < 8; ++ss) {
                const float* pr = &part[(bbu * 8 + ss) * 33];
                v0 += pr[0 * 8 + jju];
                v1 += pr[1 * 8 + jju];
                v2 += pr[2 * 8 + jju];
                v3 += pr[3 * 8 + jju];
            }
            float I  = fast_sigmoid(v0);
            float F  = fast_sigmoid(v1);
            float O  = fast_sigmoid(v2);
            float Cd = fast_tanh(v3);
            cst = fmaf(F, cst, I * Cd);
            float h = O * fast_tanh(cst);
            p.hbuf[(size_t)((t + 1) & 1) * BSZ * HH + (b0 + bbu) * HH + ju] = h;
            p.Y[((size_t)(b0 + bbu) * TT + t) * HH + ju] = h;
        }
        __syncthreads();   // drains all waves' h stores (vmcnt) + part reads done

        // ---- 8. publish: tid0 agent-scope release (wbl2 covers same-XCD L2) ----
        if (tid == 0) {
            __hip_atomic_fetch_add(ctrp, 1u, __ATOMIC_RELEASE, __HIP_MEMORY_SCOPE_AGENT);
        }
    }
}

extern "C" void kernel_launch(void* const* d_in, const int* in_sizes, int n_in,
                              void* d_out, int out_size, void* d_ws, size_t ws_size,
                              hipStream_t stream) {
    Params p;
    p.X       = (const float*)d_in[0];
    p.Wx[0]   = (const float*)d_in[1];
    p.Wh[0]   = (const float*)d_in[2];
    p.bias[0] = (const float*)d_in[3];
    p.Wx[1]   = (const float*)d_in[4];
    p.Wh[1]   = (const float*)d_in[5];
    p.bias[1] = (const float*)d_in[6];
    p.Wx[2]   = (const float*)d_in[7];
    p.Wh[2]   = (const float*)d_in[8];
    p.bias[2] = (const float*)d_in[9];
    p.Wx[3]   = (const float*)d_in[10];
    p.Wh[3]   = (const float*)d_in[11];
    p.bias[3] = (const float*)d_in[12];
    p.Y       = (float*)d_out;
    p.hbuf    = (float*)d_ws;
    p.ctr     = (unsigned int*)((char*)d_ws + (size_t)2 * BSZ * HH * sizeof(float));

    // ws is poisoned 0xAA before every timed launch: zero h0 double-buffer + counters
    init_ws<<<64, 256, 0, stream>>>(p.hbuf, p.ctr);

    lstm_persist<<<dim3(256), dim3(256), 0, stream>>>(p);
}